// Round 1
// baseline (3391.379 us; speedup 1.0000x reference)
//
#include <hip/hip_runtime.h>
#include <math.h>

#define NRES 768
#define C    128
#define LNEPS 1e-5f

// round-to-nearest-even f32 -> bf16 (top 16 bits)
__device__ __forceinline__ uint32_t bf16rn(float f) {
    uint32_t u = __float_as_uint(f);
    return (u + 0x7FFFu + ((u >> 16) & 1u)) >> 16;
}
__device__ __forceinline__ float bfhi(uint32_t u) { return __uint_as_float(u & 0xFFFF0000u); }
__device__ __forceinline__ float bflo(uint32_t u) { return __uint_as_float(u << 16); }

// sum-reduce two values across a 128-thread "quarter" (2 waves) of a 512-thread block.
// red must have 16 floats. Caller must have a __syncthreads() between successive calls
// (the loop-end barrier serves).
__device__ __forceinline__ void quarter_reduce2(float v1, float v2, float* red,
                                                int wave, int lane, int q,
                                                float& o1, float& o2) {
#pragma unroll
    for (int off = 32; off; off >>= 1) {
        v1 += __shfl_xor(v1, off, 64);
        v2 += __shfl_xor(v2, off, 64);
    }
    if (lane == 0) { red[wave * 2] = v1; red[wave * 2 + 1] = v2; }
    __syncthreads();
    o1 = red[q * 4 + 0] + red[q * 4 + 2];
    o2 = red[q * 4 + 1] + red[q * 4 + 3];
}

// Phase A: line[i,k] = sum_a proj(LN(act[a,i,:])) * sigmoid(gate(LN(act[a,i,:]))) [* mask[a,i]]
template <int RIGHT>
__global__ __launch_bounds__(512) void line_kernel(
    const float* __restrict__ act,   // [768,768,128]
    const float* __restrict__ mask,  // [768,768] (RIGHT only)
    const float* __restrict__ ln_g, const float* __restrict__ ln_b,
    const float* __restrict__ wP, const float* __restrict__ bP,
    const float* __restrict__ wG, const float* __restrict__ bG,
    float* __restrict__ line)        // [768,128]
{
    __shared__ uint32_t sWP[64 * C];  // packed bf16 pairs (c even: hi, c odd: lo), [c/2][k]
    __shared__ uint32_t sWG[64 * C];
    __shared__ float    sX[4 * C];
    __shared__ float    sRed[16];

    const int tid  = threadIdx.x;
    const int k    = tid & (C - 1);
    const int q    = tid >> 7;    // 0..3: which row-in-flight
    const int wave = tid >> 6;    // 0..7
    const int lane = tid & 63;
    const int i    = blockIdx.x;

    for (int idx = tid; idx < 64 * C; idx += 512) {
        int cp = idx >> 7, kk = idx & (C - 1);
        sWP[idx] = (bf16rn(wP[(2 * cp) * C + kk]) << 16) | bf16rn(wP[(2 * cp + 1) * C + kk]);
        sWG[idx] = (bf16rn(wG[(2 * cp) * C + kk]) << 16) | bf16rn(wG[(2 * cp + 1) * C + kk]);
    }
    const float gk  = ln_g[k];
    const float bk  = ln_b[k];
    const float bPk = bP[k];
    const float bGk = bG[k];
    __syncthreads();

    float acc = 0.f;
    for (int a = q; a < NRES; a += 4) {
        const float x = act[(size_t)a * (NRES * C) + (size_t)i * C + k];
        float sum, sumsq;
        quarter_reduce2(x, x * x, sRed, wave, lane, q, sum, sumsq);
        const float m   = sum * (1.f / C);
        const float m2  = sumsq * (1.f / C);
        const float inv = rsqrtf(m2 - m * m + LNEPS);
        sX[q * C + k]   = (x - m) * inv * gk + bk;
        __syncthreads();

        const float2* xq = (const float2*)(sX + q * C);
        float dP0 = 0.f, dP1 = 0.f, dG0 = 0.f, dG1 = 0.f;
#pragma unroll 8
        for (int cp = 0; cp < 64; ++cp) {
            float2   xc = xq[cp];
            uint32_t uP = sWP[cp * C + k];
            uint32_t uG = sWG[cp * C + k];
            dP0 += xc.x * bfhi(uP); dP1 += xc.y * bflo(uP);
            dG0 += xc.x * bfhi(uG); dG1 += xc.y * bflo(uG);
        }
        const float dotP = dP0 + dP1 + bPk;
        const float dotG = dG0 + dG1 + bGk;
        float val = dotP * (1.f / (1.f + __expf(-dotG)));
        if (RIGHT) val *= mask[(size_t)a * NRES + i];
        acc += val;
        __syncthreads();
    }

    // combine the 4 quarters
    sX[q * C + k] = acc;
    __syncthreads();
    if (q == 0)
        line[(size_t)i * C + k] = sX[k] + sX[C + k] + sX[2 * C + k] + sX[3 * C + k];
}

// Phase B: out[i,j,:] = LN(left_line[i,:] * right_line[j,:]) @ w_out + b_out
__global__ __launch_bounds__(512) void out_kernel(
    const float* __restrict__ left_line,   // [768,128]
    const float* __restrict__ right_line,  // [768,128]
    const float* __restrict__ cg, const float* __restrict__ cb,
    const float* __restrict__ w_out, const float* __restrict__ b_out,
    float* __restrict__ out)               // [768,768,128]
{
    __shared__ uint32_t sW[64 * C];
    __shared__ float    sP[4 * C];
    __shared__ float    sRed[16];
    __shared__ float    sL[C];

    const int tid  = threadIdx.x;
    const int k    = tid & (C - 1);
    const int q    = tid >> 7;
    const int wave = tid >> 6;
    const int lane = tid & 63;
    const int i    = blockIdx.x;

    for (int idx = tid; idx < 64 * C; idx += 512) {
        int cp = idx >> 7, kk = idx & (C - 1);
        sW[idx] = (bf16rn(w_out[(2 * cp) * C + kk]) << 16) | bf16rn(w_out[(2 * cp + 1) * C + kk]);
    }
    if (tid < C) sL[tid] = left_line[(size_t)i * C + tid];
    const float gk  = cg[k];
    const float bbk = cb[k];
    const float bok = b_out[k];
    __syncthreads();

    const float lk = sL[k];
    for (int j = q; j < NRES; j += 4) {
        const float p = lk * right_line[(size_t)j * C + k];
        float sum, sumsq;
        quarter_reduce2(p, p * p, sRed, wave, lane, q, sum, sumsq);
        const float m   = sum * (1.f / C);
        const float m2  = sumsq * (1.f / C);
        const float inv = rsqrtf(m2 - m * m + LNEPS);
        sP[q * C + k]   = (p - m) * inv * gk + bbk;
        __syncthreads();

        const float2* xq = (const float2*)(sP + q * C);
        float o0 = 0.f, o1 = 0.f;
#pragma unroll 8
        for (int cp = 0; cp < 64; ++cp) {
            float2   xc = xq[cp];
            uint32_t u  = sW[cp * C + k];
            o0 += xc.x * bfhi(u);
            o1 += xc.y * bflo(u);
        }
        out[((size_t)i * NRES + j) * C + k] = o0 + o1 + bok;
        __syncthreads();
    }
}

extern "C" void kernel_launch(void* const* d_in, const int* in_sizes, int n_in,
                              void* d_out, int out_size, void* d_ws, size_t ws_size,
                              hipStream_t stream) {
    const float* act_s = (const float*)d_in[0];
    const float* act_r = (const float*)d_in[1];
    const float* mask  = (const float*)d_in[2];
    const float* ln_g  = (const float*)d_in[3];
    const float* ln_b  = (const float*)d_in[4];
    const float* w_lp  = (const float*)d_in[5];
    const float* b_lp  = (const float*)d_in[6];
    const float* w_rp  = (const float*)d_in[7];
    const float* b_rp  = (const float*)d_in[8];
    const float* w_lg  = (const float*)d_in[9];
    const float* b_lg  = (const float*)d_in[10];
    const float* w_rg  = (const float*)d_in[11];
    const float* b_rg  = (const float*)d_in[12];
    const float* ln_cg = (const float*)d_in[13];
    const float* ln_cb = (const float*)d_in[14];
    const float* w_out = (const float*)d_in[15];
    const float* b_out = (const float*)d_in[16];
    float* out = (float*)d_out;

    float* left_line  = (float*)d_ws;           // 768*128 f32
    float* right_line = left_line + NRES * C;   // 768*128 f32

    line_kernel<0><<<NRES, 512, 0, stream>>>(act_s, nullptr, ln_g, ln_b,
                                             w_lp, b_lp, w_lg, b_lg, left_line);
    line_kernel<1><<<NRES, 512, 0, stream>>>(act_r, mask, ln_g, ln_b,
                                             w_rp, b_rp, w_rg, b_rg, right_line);
    out_kernel<<<NRES, 512, 0, stream>>>(left_line, right_line, ln_cg, ln_cb,
                                         w_out, b_out, out);
}

// Round 3
// 440.597 us; speedup vs baseline: 7.6972x; 7.6972x over previous
//
#include <hip/hip_runtime.h>
#include <math.h>

#define NRES 768
#define C    128
#define LNEPS 1e-5f
#define TA   16      // a-values per block (phase A)
#define ACH  48      // a-chunks = 768/TA

typedef __attribute__((ext_vector_type(8))) short bf16x8;
typedef __attribute__((ext_vector_type(4))) float f32x4;

// round-to-nearest-even f32 -> bf16 bits (low 16 of return)
__device__ __forceinline__ uint32_t bf16rn(float f) {
    uint32_t u = __float_as_uint(f);
    return (u + 0x7FFFu + ((u >> 16) & 1u)) >> 16;
}

// pack two f32 into bf16 pair words: hi-part and lo-part (x ~= hi + lo)
__device__ __forceinline__ void split2(float a, float b, uint32_t& hi, uint32_t& lo) {
    uint32_t ha = bf16rn(a), hb = bf16rn(b);
    float ra = a - __uint_as_float(ha << 16);
    float rb = b - __uint_as_float(hb << 16);
    hi = ha | (hb << 16);
    lo = bf16rn(ra) | (bf16rn(rb) << 16);
}

__device__ __forceinline__ void halfwave_reduce2(float& s, float& s2) {
#pragma unroll
    for (int m = 1; m <= 16; m <<= 1) {
        s  += __shfl_xor(s,  m);
        s2 += __shfl_xor(s2, m);
    }
}

// ---------------------------------------------------------------------------
// Phase A: partial line sums.
// line[i,c] = sum_a [mask[a,i]] * P(a,i,c) * sigmoid(G(a,i,c))
// [P|G](a,i,:) = LN(act[a,i,:]) @ [wP|wG] + [bP|bG]
// Block: 256 thr / 4 waves, 64 i-rows, TA a-values. Waves split N=256
// (wave w: P cols w*32..+32 and G cols w*32..+32) so gating is register-local.
// Activations split hi/lo bf16 (~fp32 precision); weights single bf16.
// ---------------------------------------------------------------------------
template <int RIGHT>
__global__ __launch_bounds__(256, 2) void line_mfma(
    const float* __restrict__ act,   // [768,768,128]
    const float* __restrict__ mask,  // [768,768] (RIGHT only)
    const float* __restrict__ ln_g, const float* __restrict__ ln_b,
    const float* __restrict__ wP, const float* __restrict__ bP,
    const float* __restrict__ wG, const float* __restrict__ bG,
    float* __restrict__ part)        // [ACH][768][128]
{
    __shared__ char  sXhi[64 * 256];  // bf16 [64 rows][128 c], XOR-swizzled
    __shared__ char  sXlo[64 * 256];
    __shared__ float sM[TA * 64];

    const int t = threadIdx.x;
    const int w = t >> 6;            // wave 0..3
    const int l = t & 63;
    const int i0  = (blockIdx.x % 12) * 64;
    const int ach = blockIdx.x / 12;
    const int a0  = ach * TA;

    // --- B-fragments (weights) -> registers, held for the whole kernel ---
    // B[k][n]: lane holds k = kk*32 + (l>>4)*8 + jj, n = tile_col + (l&15)
    bf16x8 bfr[4][4];                // [nt][kk]; nt 0,1 = P, nt 2,3 = G
#pragma unroll
    for (int nt = 0; nt < 4; ++nt) {
        const float* wsrc = (nt < 2) ? wP : wG;
        const int n = w * 32 + (nt & 1) * 16 + (l & 15);
#pragma unroll
        for (int kk = 0; kk < 4; ++kk) {
            bf16x8 f;
#pragma unroll
            for (int jj = 0; jj < 8; ++jj) {
                const int k = kk * 32 + (l >> 4) * 8 + jj;
                f[jj] = (short)bf16rn(wsrc[k * C + n]);
            }
            bfr[nt][kk] = f;
        }
    }
    float biasP[2], biasG[2];
#pragma unroll
    for (int ntp = 0; ntp < 2; ++ntp) {
        biasP[ntp] = bP[w * 32 + ntp * 16 + (l & 15)];
        biasG[ntp] = bG[w * 32 + ntp * 16 + (l & 15)];
    }
    const int c4 = 4 * (t & 31);
    const float4 g4 = *(const float4*)(ln_g + c4);
    const float4 b4 = *(const float4*)(ln_b + c4);

    if (RIGHT) {
        for (int idx = t; idx < TA * 64; idx += 256)
            sM[idx] = mask[(size_t)(a0 + (idx >> 6)) * NRES + i0 + (idx & 63)];
    }

    float lacc[4][2][4];
#pragma unroll
    for (int mt = 0; mt < 4; ++mt)
#pragma unroll
        for (int ntp = 0; ntp < 2; ++ntp)
#pragma unroll
            for (int jr = 0; jr < 4; ++jr) lacc[mt][ntp][jr] = 0.f;

    __syncthreads();

    for (int al = 0; al < TA; ++al) {
        const float* src = act + (size_t)(a0 + al) * (NRES * C) + (size_t)i0 * C;
        float4 xv[8];
#pragma unroll
        for (int j = 0; j < 8; ++j)
            xv[j] = *(const float4*)(src + 4 * (t + 256 * j));

        // LN rows: thread t holds cols c4..c4+3 of row (t>>5)+8j
#pragma unroll
        for (int j = 0; j < 8; ++j) {
            float4 x = xv[j];
            float s  = x.x + x.y + x.z + x.w;
            float s2 = x.x * x.x + x.y * x.y + x.z * x.z + x.w * x.w;
            halfwave_reduce2(s, s2);
            const float mean = s * (1.f / C);
            const float var  = s2 * (1.f / C) - mean * mean;
            const float inv  = rsqrtf(var + LNEPS);
            const float n0 = (x.x - mean) * inv * g4.x + b4.x;
            const float n1 = (x.y - mean) * inv * g4.y + b4.y;
            const float n2 = (x.z - mean) * inv * g4.z + b4.z;
            const float n3 = (x.w - mean) * inv * g4.w + b4.w;
            const int row  = (t >> 5) + 8 * j;
            const int byte = (row * 256 + 8 * (t & 31)) ^ ((row & 7) << 4);
            uint2 uh, ul;
            split2(n0, n1, uh.x, ul.x);
            split2(n2, n3, uh.y, ul.y);
            *(uint2*)(sXhi + byte) = uh;
            *(uint2*)(sXlo + byte) = ul;
        }
        __syncthreads();

        const f32x4 zero = {0.f, 0.f, 0.f, 0.f};
#pragma unroll
        for (int mt = 0; mt < 4; ++mt) {
            bf16x8 ah[4], alo[4];
#pragma unroll
            for (int kk = 0; kk < 4; ++kk) {
                const int row  = mt * 16 + (l & 15);
                const int byte = (row * 256 + (kk * 32 + (l >> 4) * 8) * 2) ^ ((row & 7) << 4);
                ah[kk]  = *(const bf16x8*)(sXhi + byte);
                alo[kk] = *(const bf16x8*)(sXlo + byte);
            }
            f32x4 acc[4];
#pragma unroll
            for (int nt = 0; nt < 4; ++nt) acc[nt] = zero;
#pragma unroll
            for (int nt = 0; nt < 4; ++nt)
#pragma unroll
                for (int kk = 0; kk < 4; ++kk) {
                    acc[nt] = __builtin_amdgcn_mfma_f32_16x16x32_bf16(
                        ah[kk], bfr[nt][kk], acc[nt], 0, 0, 0);
                    acc[nt] = __builtin_amdgcn_mfma_f32_16x16x32_bf16(
                        alo[kk], bfr[nt][kk], acc[nt], 0, 0, 0);
                }

            // gate + accumulate
            float mk[4] = {1.f, 1.f, 1.f, 1.f};
            if (RIGHT) {
                const float4 m4 = *(const float4*)&sM[al * 64 + mt * 16 + (l >> 4) * 4];
                mk[0] = m4.x; mk[1] = m4.y; mk[2] = m4.z; mk[3] = m4.w;
            }
#pragma unroll
            for (int ntp = 0; ntp < 2; ++ntp)
#pragma unroll
                for (int jr = 0; jr < 4; ++jr) {
                    const float P = acc[ntp][jr] + biasP[ntp];
                    const float G = acc[ntp + 2][jr] + biasG[ntp];
                    const float sg = __builtin_amdgcn_rcpf(1.f + __expf(-G));
                    lacc[mt][ntp][jr] += P * sg * mk[jr];
                }
        }
        __syncthreads();
    }

    float* dst = part + (size_t)ach * (NRES * C);
#pragma unroll
    for (int mt = 0; mt < 4; ++mt)
#pragma unroll
        for (int ntp = 0; ntp < 2; ++ntp)
#pragma unroll
            for (int jr = 0; jr < 4; ++jr)
                dst[(size_t)(i0 + mt * 16 + (l >> 4) * 4 + jr) * C +
                    w * 32 + ntp * 16 + (l & 15)] = lacc[mt][ntp][jr];
}

__global__ __launch_bounds__(256) void reduce_part(const float* __restrict__ part,
                                                   float* __restrict__ line) {
    const int idx = blockIdx.x * 256 + threadIdx.x;  // 98304 total
    float s = 0.f;
#pragma unroll 8
    for (int p = 0; p < ACH; ++p) s += part[(size_t)p * (NRES * C) + idx];
    line[idx] = s;
}

// ---------------------------------------------------------------------------
// Phase B: out[i,j,:] = LN(l[i,:]*r[j,:]) @ w_out + b_out
// Block: 256 thr / 4 waves, one i, 64 j's. Waves split N=128 (32 cols each).
// ---------------------------------------------------------------------------
__global__ __launch_bounds__(256, 2) void out_mfma(
    const float* __restrict__ lline,   // [768,128]
    const float* __restrict__ rline,   // [768,128]
    const float* __restrict__ cg, const float* __restrict__ cb,
    const float* __restrict__ wO, const float* __restrict__ bO,
    float* __restrict__ out)           // [768,768,128]
{
    __shared__ char sXhi[64 * 256];
    __shared__ char sXlo[64 * 256];

    const int t = threadIdx.x;
    const int w = t >> 6;
    const int l = t & 63;
    const int i  = blockIdx.x / 12;
    const int j0 = (blockIdx.x % 12) * 64;

    bf16x8 bfr[2][4];
#pragma unroll
    for (int nt = 0; nt < 2; ++nt) {
        const int n = w * 32 + nt * 16 + (l & 15);
#pragma unroll
        for (int kk = 0; kk < 4; ++kk) {
            bf16x8 f;
#pragma unroll
            for (int jj = 0; jj < 8; ++jj) {
                const int k = kk * 32 + (l >> 4) * 8 + jj;
                f[jj] = (short)bf16rn(wO[k * C + n]);
            }
            bfr[nt][kk] = f;
        }
    }
    float biasO[2];
#pragma unroll
    for (int nt = 0; nt < 2; ++nt) biasO[nt] = bO[w * 32 + nt * 16 + (l & 15)];

    const int c4 = 4 * (t & 31);
    const float4 g4 = *(const float4*)(cg + c4);
    const float4 b4 = *(const float4*)(cb + c4);
    const float4 l4 = *(const float4*)(lline + (size_t)i * C + c4);

    const float* rsrc = rline + (size_t)j0 * C;
    float4 rv[8];
#pragma unroll
    for (int j = 0; j < 8; ++j)
        rv[j] = *(const float4*)(rsrc + 4 * (t + 256 * j));

#pragma unroll
    for (int j = 0; j < 8; ++j) {
        float4 p;
        p.x = l4.x * rv[j].x; p.y = l4.y * rv[j].y;
        p.z = l4.z * rv[j].z; p.w = l4.w * rv[j].w;
        float s  = p.x + p.y + p.z + p.w;
        float s2 = p.x * p.x + p.y * p.y + p.z * p.z + p.w * p.w;
        halfwave_reduce2(s, s2);
        const float mean = s * (1.f / C);
        const float var  = s2 * (1.f / C) - mean * mean;
        const float inv  = rsqrtf(var + LNEPS);
        const float n0 = (p.x - mean) * inv * g4.x + b4.x;
        const float n1 = (p.y - mean) * inv * g4.y + b4.y;
        const float n2 = (p.z - mean) * inv * g4.z + b4.z;
        const float n3 = (p.w - mean) * inv * g4.w + b4.w;
        const int row  = (t >> 5) + 8 * j;
        const int byte = (row * 256 + 8 * (t & 31)) ^ ((row & 7) << 4);
        uint2 uh, ul;
        split2(n0, n1, uh.x, ul.x);
        split2(n2, n3, uh.y, ul.y);
        *(uint2*)(sXhi + byte) = uh;
        *(uint2*)(sXlo + byte) = ul;
    }
    __syncthreads();

    const f32x4 zero = {0.f, 0.f, 0.f, 0.f};
#pragma unroll
    for (int mt = 0; mt < 4; ++mt) {
        bf16x8 ah[4], alo[4];
#pragma unroll
        for (int kk = 0; kk < 4; ++kk) {
            const int row  = mt * 16 + (l & 15);
            const int byte = (row * 256 + (kk * 32 + (l >> 4) * 8) * 2) ^ ((row & 7) << 4);
            ah[kk]  = *(const bf16x8*)(sXhi + byte);
            alo[kk] = *(const bf16x8*)(sXlo + byte);
        }
        f32x4 acc[2];
#pragma unroll
        for (int nt = 0; nt < 2; ++nt) acc[nt] = zero;
#pragma unroll
        for (int nt = 0; nt < 2; ++nt)
#pragma unroll
            for (int kk = 0; kk < 4; ++kk) {
                acc[nt] = __builtin_amdgcn_mfma_f32_16x16x32_bf16(
                    ah[kk], bfr[nt][kk], acc[nt], 0, 0, 0);
                acc[nt] = __builtin_amdgcn_mfma_f32_16x16x32_bf16(
                    alo[kk], bfr[nt][kk], acc[nt], 0, 0, 0);
            }
#pragma unroll
        for (int nt = 0; nt < 2; ++nt)
#pragma unroll
            for (int jr = 0; jr < 4; ++jr)
                out[((size_t)i * NRES + j0 + mt * 16 + (l >> 4) * 4 + jr) * C +
                    w * 32 + nt * 16 + (l & 15)] = acc[nt][jr] + biasO[nt];
    }
}

extern "C" void kernel_launch(void* const* d_in, const int* in_sizes, int n_in,
                              void* d_out, int out_size, void* d_ws, size_t ws_size,
                              hipStream_t stream) {
    const float* act_s = (const float*)d_in[0];
    const float* act_r = (const float*)d_in[1];
    const float* mask  = (const float*)d_in[2];
    const float* ln_g  = (const float*)d_in[3];
    const float* ln_b  = (const float*)d_in[4];
    const float* w_lp  = (const float*)d_in[5];
    const float* b_lp  = (const float*)d_in[6];
    const float* w_rp  = (const float*)d_in[7];
    const float* b_rp  = (const float*)d_in[8];
    const float* w_lg  = (const float*)d_in[9];
    const float* b_lg  = (const float*)d_in[10];
    const float* w_rg  = (const float*)d_in[11];
    const float* b_rg  = (const float*)d_in[12];
    const float* ln_cg = (const float*)d_in[13];
    const float* ln_cb = (const float*)d_in[14];
    const float* w_out = (const float*)d_in[15];
    const float* b_out = (const float*)d_in[16];
    float* out = (float*)d_out;

    float* part       = (float*)d_ws;              // [ACH][768][128]
    float* left_line  = part + (size_t)ACH * NRES * C;
    float* right_line = left_line + NRES * C;

    line_mfma<0><<<ACH * 12, 256, 0, stream>>>(act_s, nullptr, ln_g, ln_b,
                                               w_lp, b_lp, w_lg, b_lg, part);
    reduce_part<<<NRES * C / 256, 256, 0, stream>>>(part, left_line);
    line_mfma<1><<<ACH * 12, 256, 0, stream>>>(act_r, mask, ln_g, ln_b,
                                               w_rp, b_rp, w_rg, b_rg, part);
    reduce_part<<<NRES * C / 256, 256, 0, stream>>>(part, right_line);
    out_mfma<<<NRES * 12, 256, 0, stream>>>(left_line, right_line, ln_cg, ln_cb,
                                            w_out, b_out, out);
}

// Round 4
// 412.991 us; speedup vs baseline: 8.2117x; 1.0668x over previous
//
#include <hip/hip_runtime.h>
#include <math.h>

#define NRES 768
#define C    128
#define LNEPS 1e-5f
#define TA   16      // a-values per block (phase A)
#define ACH  48      // a-chunks = 768/TA
#define MI   32      // i-rows per block (phase A)
#define NIT  (NRES / MI)   // 24 i-tiles

typedef __attribute__((ext_vector_type(8))) short bf16x8;
typedef __attribute__((ext_vector_type(4))) float f32x4;

// round-to-nearest-even f32 -> bf16 bits (low 16 of return)
__device__ __forceinline__ uint32_t bf16rn(float f) {
    uint32_t u = __float_as_uint(f);
    return (u + 0x7FFFu + ((u >> 16) & 1u)) >> 16;
}

// pack two f32 into bf16 pair words: hi-part and lo-part (x ~= hi + lo)
__device__ __forceinline__ void split2(float a, float b, uint32_t& hi, uint32_t& lo) {
    uint32_t ha = bf16rn(a), hb = bf16rn(b);
    float ra = a - __uint_as_float(ha << 16);
    float rb = b - __uint_as_float(hb << 16);
    hi = ha | (hb << 16);
    lo = bf16rn(ra) | (bf16rn(rb) << 16);
}

__device__ __forceinline__ void halfwave_reduce2(float& s, float& s2) {
#pragma unroll
    for (int m = 1; m <= 16; m <<= 1) {
        s  += __shfl_xor(s,  m);
        s2 += __shfl_xor(s2, m);
    }
}

// ---------------------------------------------------------------------------
// Phase A: partial line sums.
// line[i,c] = sum_a [mask[a,i]] * P(a,i,c) * sigmoid(G(a,i,c))
// [P|G](a,i,:) = LN(act[a,i,:]) @ [wP|wG] + [bP|bG]
// Block: 256 thr / 4 waves, MI=32 i-rows, TA a-values. Waves split N=256
// (wave w: P cols w*32..+32 and G cols w*32..+32) so gating is register-local.
// Activations split hi/lo bf16 (~fp32 precision); weights single bf16.
// Global loads for a-step al+1 are issued before the MFMA of step al
// (prefetch) so HBM latency hides under compute.
// ---------------------------------------------------------------------------
template <int RIGHT>
__global__ __launch_bounds__(256, 3) void line_mfma(
    const float* __restrict__ act,   // [768,768,128]
    const float* __restrict__ mask,  // [768,768] (RIGHT only)
    const float* __restrict__ ln_g, const float* __restrict__ ln_b,
    const float* __restrict__ wP, const float* __restrict__ bP,
    const float* __restrict__ wG, const float* __restrict__ bG,
    float* __restrict__ part)        // [ACH][768][128]
{
    __shared__ char  sXhi[MI * 256];  // bf16 [32 rows][128 c], XOR-swizzled
    __shared__ char  sXlo[MI * 256];
    __shared__ float sM[TA * MI];

    const int t = threadIdx.x;
    const int w = t >> 6;            // wave 0..3
    const int l = t & 63;
    const int i0  = (blockIdx.x % NIT) * MI;
    const int ach = blockIdx.x / NIT;
    const int a0  = ach * TA;

    // --- B-fragments (weights) -> registers, held for the whole kernel ---
    // B[k][n]: lane holds k = kk*32 + (l>>4)*8 + jj, n = tile_col + (l&15)
    bf16x8 bfr[4][4];                // [nt][kk]; nt 0,1 = P, nt 2,3 = G
#pragma unroll
    for (int nt = 0; nt < 4; ++nt) {
        const float* wsrc = (nt < 2) ? wP : wG;
        const int n = w * 32 + (nt & 1) * 16 + (l & 15);
#pragma unroll
        for (int kk = 0; kk < 4; ++kk) {
            bf16x8 f;
#pragma unroll
            for (int jj = 0; jj < 8; ++jj) {
                const int k = kk * 32 + (l >> 4) * 8 + jj;
                f[jj] = (short)bf16rn(wsrc[k * C + n]);
            }
            bfr[nt][kk] = f;
        }
    }
    float biasP[2], biasG[2];
#pragma unroll
    for (int ntp = 0; ntp < 2; ++ntp) {
        biasP[ntp] = bP[w * 32 + ntp * 16 + (l & 15)];
        biasG[ntp] = bG[w * 32 + ntp * 16 + (l & 15)];
    }
    const int c4 = 4 * (t & 31);
    const float4 g4 = *(const float4*)(ln_g + c4);
    const float4 b4 = *(const float4*)(ln_b + c4);

    if (RIGHT) {
        for (int idx = t; idx < TA * MI; idx += 256)
            sM[idx] = mask[(size_t)(a0 + (idx >> 5)) * NRES + i0 + (idx & 31)];
    }

    float lacc[2][2][4];
#pragma unroll
    for (int mt = 0; mt < 2; ++mt)
#pragma unroll
        for (int ntp = 0; ntp < 2; ++ntp)
#pragma unroll
            for (int jr = 0; jr < 4; ++jr) lacc[mt][ntp][jr] = 0.f;

    const float* srcbase = act + (size_t)a0 * (NRES * C) + (size_t)i0 * C;
    float4 xv[4], xn[4];
#pragma unroll
    for (int j = 0; j < 4; ++j)
        xv[j] = *(const float4*)(srcbase + 4 * (t + 256 * j));

    __syncthreads();

    for (int al = 0; al < TA; ++al) {
        // prefetch next a-step (latency hides under LN+MFMA+gate)
        if (al + 1 < TA) {
            const float* srcn = srcbase + (size_t)(al + 1) * (NRES * C);
#pragma unroll
            for (int j = 0; j < 4; ++j)
                xn[j] = *(const float4*)(srcn + 4 * (t + 256 * j));
        }

        // LN rows: thread t holds cols c4..c4+3 of row (t>>5)+8j
#pragma unroll
        for (int j = 0; j < 4; ++j) {
            float4 x = xv[j];
            float s  = x.x + x.y + x.z + x.w;
            float s2 = x.x * x.x + x.y * x.y + x.z * x.z + x.w * x.w;
            halfwave_reduce2(s, s2);
            const float mean = s * (1.f / C);
            const float var  = s2 * (1.f / C) - mean * mean;
            const float inv  = rsqrtf(var + LNEPS);
            const float n0 = (x.x - mean) * inv * g4.x + b4.x;
            const float n1 = (x.y - mean) * inv * g4.y + b4.y;
            const float n2 = (x.z - mean) * inv * g4.z + b4.z;
            const float n3 = (x.w - mean) * inv * g4.w + b4.w;
            const int row  = (t >> 5) + 8 * j;
            const int byte = (row * 256 + 8 * (t & 31)) ^ ((row & 7) << 4);
            uint2 uh, ul;
            split2(n0, n1, uh.x, ul.x);
            split2(n2, n3, uh.y, ul.y);
            *(uint2*)(sXhi + byte) = uh;
            *(uint2*)(sXlo + byte) = ul;
        }
        __syncthreads();

        const f32x4 zero = {0.f, 0.f, 0.f, 0.f};
#pragma unroll
        for (int mt = 0; mt < 2; ++mt) {
            bf16x8 ah[4], alo[4];
#pragma unroll
            for (int kk = 0; kk < 4; ++kk) {
                const int row  = mt * 16 + (l & 15);
                const int byte = (row * 256 + (kk * 32 + (l >> 4) * 8) * 2) ^ ((row & 7) << 4);
                ah[kk]  = *(const bf16x8*)(sXhi + byte);
                alo[kk] = *(const bf16x8*)(sXlo + byte);
            }
            f32x4 acc[4];
#pragma unroll
            for (int nt = 0; nt < 4; ++nt) acc[nt] = zero;
#pragma unroll
            for (int nt = 0; nt < 4; ++nt)
#pragma unroll
                for (int kk = 0; kk < 4; ++kk) {
                    acc[nt] = __builtin_amdgcn_mfma_f32_16x16x32_bf16(
                        ah[kk], bfr[nt][kk], acc[nt], 0, 0, 0);
                    acc[nt] = __builtin_amdgcn_mfma_f32_16x16x32_bf16(
                        alo[kk], bfr[nt][kk], acc[nt], 0, 0, 0);
                }

            // gate + accumulate
            float mk[4] = {1.f, 1.f, 1.f, 1.f};
            if (RIGHT) {
                const float4 m4 = *(const float4*)&sM[al * MI + mt * 16 + (l >> 4) * 4];
                mk[0] = m4.x; mk[1] = m4.y; mk[2] = m4.z; mk[3] = m4.w;
            }
#pragma unroll
            for (int ntp = 0; ntp < 2; ++ntp)
#pragma unroll
                for (int jr = 0; jr < 4; ++jr) {
                    const float P = acc[ntp][jr] + biasP[ntp];
                    const float G = acc[ntp + 2][jr] + biasG[ntp];
                    const float sg = __builtin_amdgcn_rcpf(1.f + __expf(-G));
                    lacc[mt][ntp][jr] += P * sg * mk[jr];
                }
        }
        __syncthreads();

#pragma unroll
        for (int j = 0; j < 4; ++j) xv[j] = xn[j];
    }

    float* dst = part + (size_t)ach * (NRES * C);
#pragma unroll
    for (int mt = 0; mt < 2; ++mt)
#pragma unroll
        for (int ntp = 0; ntp < 2; ++ntp)
#pragma unroll
            for (int jr = 0; jr < 4; ++jr)
                dst[(size_t)(i0 + mt * 16 + (l >> 4) * 4 + jr) * C +
                    w * 32 + ntp * 16 + (l & 15)] = lacc[mt][ntp][jr];
}

__global__ __launch_bounds__(256) void reduce_part(const float* __restrict__ part,
                                                   float* __restrict__ line) {
    const int idx = blockIdx.x * 256 + threadIdx.x;  // 98304 total
    float s = 0.f;
#pragma unroll 8
    for (int p = 0; p < ACH; ++p) s += part[(size_t)p * (NRES * C) + idx];
    line[idx] = s;
}

// ---------------------------------------------------------------------------
// Phase B: out[i,j,:] = LN(l[i,:]*r[j,:]) @ w_out + b_out
// Block: 256 thr / 4 waves, one i, 64 j's. Waves split N=128 (32 cols each).
// ---------------------------------------------------------------------------
__global__ __launch_bounds__(256, 2) void out_mfma(
    const float* __restrict__ lline,   // [768,128]
    const float* __restrict__ rline,   // [768,128]
    const float* __restrict__ cg, const float* __restrict__ cb,
    const float* __restrict__ wO, const float* __restrict__ bO,
    float* __restrict__ out)           // [768,768,128]
{
    __shared__ char sXhi[64 * 256];
    __shared__ char sXlo[64 * 256];

    const int t = threadIdx.x;
    const int w = t >> 6;
    const int l = t & 63;
    const int i  = blockIdx.x / 12;
    const int j0 = (blockIdx.x % 12) * 64;

    bf16x8 bfr[2][4];
#pragma unroll
    for (int nt = 0; nt < 2; ++nt) {
        const int n = w * 32 + nt * 16 + (l & 15);
#pragma unroll
        for (int kk = 0; kk < 4; ++kk) {
            bf16x8 f;
#pragma unroll
            for (int jj = 0; jj < 8; ++jj) {
                const int k = kk * 32 + (l >> 4) * 8 + jj;
                f[jj] = (short)bf16rn(wO[k * C + n]);
            }
            bfr[nt][kk] = f;
        }
    }
    float biasO[2];
#pragma unroll
    for (int nt = 0; nt < 2; ++nt) biasO[nt] = bO[w * 32 + nt * 16 + (l & 15)];

    const int c4 = 4 * (t & 31);
    const float4 g4 = *(const float4*)(cg + c4);
    const float4 b4 = *(const float4*)(cb + c4);
    const float4 l4 = *(const float4*)(lline + (size_t)i * C + c4);

    const float* rsrc = rline + (size_t)j0 * C;
    float4 rv[8];
#pragma unroll
    for (int j = 0; j < 8; ++j)
        rv[j] = *(const float4*)(rsrc + 4 * (t + 256 * j));

#pragma unroll
    for (int j = 0; j < 8; ++j) {
        float4 p;
        p.x = l4.x * rv[j].x; p.y = l4.y * rv[j].y;
        p.z = l4.z * rv[j].z; p.w = l4.w * rv[j].w;
        float s  = p.x + p.y + p.z + p.w;
        float s2 = p.x * p.x + p.y * p.y + p.z * p.z + p.w * p.w;
        halfwave_reduce2(s, s2);
        const float mean = s * (1.f / C);
        const float var  = s2 * (1.f / C) - mean * mean;
        const float inv  = rsqrtf(var + LNEPS);
        const float n0 = (p.x - mean) * inv * g4.x + b4.x;
        const float n1 = (p.y - mean) * inv * g4.y + b4.y;
        const float n2 = (p.z - mean) * inv * g4.z + b4.z;
        const float n3 = (p.w - mean) * inv * g4.w + b4.w;
        const int row  = (t >> 5) + 8 * j;
        const int byte = (row * 256 + 8 * (t & 31)) ^ ((row & 7) << 4);
        uint2 uh, ul;
        split2(n0, n1, uh.x, ul.x);
        split2(n2, n3, uh.y, ul.y);
        *(uint2*)(sXhi + byte) = uh;
        *(uint2*)(sXlo + byte) = ul;
    }
    __syncthreads();

    const f32x4 zero = {0.f, 0.f, 0.f, 0.f};
#pragma unroll
    for (int mt = 0; mt < 4; ++mt) {
        bf16x8 ah[4], alo[4];
#pragma unroll
        for (int kk = 0; kk < 4; ++kk) {
            const int row  = mt * 16 + (l & 15);
            const int byte = (row * 256 + (kk * 32 + (l >> 4) * 8) * 2) ^ ((row & 7) << 4);
            ah[kk]  = *(const bf16x8*)(sXhi + byte);
            alo[kk] = *(const bf16x8*)(sXlo + byte);
        }
        f32x4 acc[2];
#pragma unroll
        for (int nt = 0; nt < 2; ++nt) acc[nt] = zero;
#pragma unroll
        for (int nt = 0; nt < 2; ++nt)
#pragma unroll
            for (int kk = 0; kk < 4; ++kk) {
                acc[nt] = __builtin_amdgcn_mfma_f32_16x16x32_bf16(
                    ah[kk], bfr[nt][kk], acc[nt], 0, 0, 0);
                acc[nt] = __builtin_amdgcn_mfma_f32_16x16x32_bf16(
                    alo[kk], bfr[nt][kk], acc[nt], 0, 0, 0);
            }
#pragma unroll
        for (int nt = 0; nt < 2; ++nt)
#pragma unroll
            for (int jr = 0; jr < 4; ++jr)
                out[((size_t)i * NRES + j0 + mt * 16 + (l >> 4) * 4 + jr) * C +
                    w * 32 + nt * 16 + (l & 15)] = acc[nt][jr] + biasO[nt];
    }
}

extern "C" void kernel_launch(void* const* d_in, const int* in_sizes, int n_in,
                              void* d_out, int out_size, void* d_ws, size_t ws_size,
                              hipStream_t stream) {
    const float* act_s = (const float*)d_in[0];
    const float* act_r = (const float*)d_in[1];
    const float* mask  = (const float*)d_in[2];
    const float* ln_g  = (const float*)d_in[3];
    const float* ln_b  = (const float*)d_in[4];
    const float* w_lp  = (const float*)d_in[5];
    const float* b_lp  = (const float*)d_in[6];
    const float* w_rp  = (const float*)d_in[7];
    const float* b_rp  = (const float*)d_in[8];
    const float* w_lg  = (const float*)d_in[9];
    const float* b_lg  = (const float*)d_in[10];
    const float* w_rg  = (const float*)d_in[11];
    const float* b_rg  = (const float*)d_in[12];
    const float* ln_cg = (const float*)d_in[13];
    const float* ln_cb = (const float*)d_in[14];
    const float* w_out = (const float*)d_in[15];
    const float* b_out = (const float*)d_in[16];
    float* out = (float*)d_out;

    float* part       = (float*)d_ws;              // [ACH][768][128]
    float* left_line  = part + (size_t)ACH * NRES * C;
    float* right_line = left_line + NRES * C;

    line_mfma<0><<<ACH * NIT, 256, 0, stream>>>(act_s, nullptr, ln_g, ln_b,
                                                w_lp, b_lp, w_lg, b_lg, part);
    reduce_part<<<NRES * C / 256, 256, 0, stream>>>(part, left_line);
    line_mfma<1><<<ACH * NIT, 256, 0, stream>>>(act_r, mask, ln_g, ln_b,
                                                w_rp, b_rp, w_rg, b_rg, part);
    reduce_part<<<NRES * C / 256, 256, 0, stream>>>(part, right_line);
    out_mfma<<<NRES * 12, 256, 0, stream>>>(left_line, right_line, ln_cg, ln_cb,
                                            w_out, b_out, out);
}